// Round 20
// baseline (20993.124 us; speedup 1.0000x reference)
//
#include <hip/hip_runtime.h>
#include <hip/hip_bf16.h>

namespace k77 {

typedef long long ll;
typedef double f64x4 __attribute__((ext_vector_type(4)));

constexpr int D    = 512;
constexpr int DTGT = 128;
constexpr int NB   = 1024;
constexpr int TS   = 64;
constexpr int TT   = 64;
constexpr int G4   = 2048;

// ---------------- runtime MFMA-f64 C/D-layout probe (r14-verified) ----------------
__global__ void probe_mfma(int* __restrict__ dlay)
{
    __shared__ double ref[256];
    __shared__ int ok[4];
    const int l = threadIdx.x;           // 64 threads
    const int l15 = l & 15, l4 = l >> 4;
    if (l < 4) ok[l] = 1;
    double a = 1.0 + 3.0 * l15 + 7.0 * l4;
    double b = 2.0 + 5.0 * l15 + 11.0 * l4;
    f64x4 d = {0.0, 0.0, 0.0, 0.0};
    d = __builtin_amdgcn_mfma_f64_16x16x4f64(a, b, d, 0, 0, 0);
    if (l < 16) {
        for (int j = 0; j < 16; ++j) {
            double s = 0.0;
            for (int k = 0; k < 4; ++k)
                s += (1.0 + 3.0 * l + 7.0 * k) * (2.0 + 5.0 * j + 11.0 * k);
            ref[l * 16 + j] = s;
        }
    }
    __syncthreads();
#pragma unroll
    for (int n = 0; n < 4; ++n) {
        if (d[n] != ref[(l4 * 4 + n) * 16 + l15]) atomicAnd(&ok[0], 0);
        if (d[n] != ref[(l4 + 4 * n) * 16 + l15]) atomicAnd(&ok[1], 0);
        if (d[n] != ref[l15 * 16 + (l4 * 4 + n)]) atomicAnd(&ok[2], 0);
        if (d[n] != ref[l15 * 16 + (l4 + 4 * n)]) atomicAnd(&ok[3], 0);
    }
    __syncthreads();
    if (l == 0) {
        int r = -1;
        for (int i = 3; i >= 0; --i) if (ok[i]) r = i;
        *dlay = r;
    }
}

__global__ void dlay_check(const int* __restrict__ dlay, float* __restrict__ out0)
{
    if (*dlay < 0)
        for (int i = threadIdx.x; i < 256; i += 64) out0[i] = 3.0e38f;
}

__device__ __forceinline__ void dmap(int dl, int l15, int l4, int n, int& r, int& c)
{
    if (dl == 1)      { r = l4 + 4 * n;  c = l15; }
    else if (dl == 2) { r = l15;         c = l4 * 4 + n; }
    else if (dl == 3) { r = l15;         c = l4 + 4 * n; }
    else              { r = l4 * 4 + n;  c = l15; }
}

// ---------------- precompute GEMM (f64 accumulate, f32 store) ----------------
__global__ void tab_gemm64(const float* __restrict__ A, const float* __restrict__ B,
                           const float* __restrict__ b1, const float* __restrict__ b2,
                           float* __restrict__ C, int M, int N, int K, int ldc, float scale, int perm)
{
    int j = blockIdx.x * 256 + threadIdx.x;
    int m = blockIdx.y;
    if (j >= N || m >= M) return;
    const float* ar = A + (size_t)m * K;
    double acc = 0.0;
    for (int k = 0; k < K; ++k) acc += (double)ar[k] * (double)B[(size_t)k * N + j];
    if (b1) acc += (double)b1[j];
    if (b2) acc += (double)b2[j];
    int j2 = perm ? ((j & 511) * 4 + (j >> 9)) : j;
    C[(size_t)m * ldc + j2] = (float)(acc * (double)scale);
}

// three 128x2048 permuted tables in one launch (z selects)
struct Tab3 { const float *A0,*A1,*A2,*B0,*B1,*B2,*p0,*p1,*p2,*q0,*q1,*q2; float *C0,*C1,*C2; };
__global__ void tab3_gemm64(Tab3 t)
{
    int j = blockIdx.x * 256 + threadIdx.x;   // 0..2047
    int m = blockIdx.y;                        // 0..127
    int z = blockIdx.z;
    const float* A  = z == 0 ? t.A0 : (z == 1 ? t.A1 : t.A2);
    const float* B  = z == 0 ? t.B0 : (z == 1 ? t.B1 : t.B2);
    const float* b1 = z == 0 ? t.p0 : (z == 1 ? t.p1 : t.p2);
    const float* b2 = z == 0 ? t.q0 : (z == 1 ? t.q1 : t.q2);
    float*       C  = z == 0 ? t.C0 : (z == 1 ? t.C1 : t.C2);
    const float* ar = A + (size_t)m * D;
    double acc = 0.0;
    for (int k = 0; k < D; ++k) acc += (double)ar[k] * (double)B[(size_t)k * G4 + j];
    acc += (double)b1[j];
    acc += (double)b2[j];
    C[(size_t)m * G4 + (j & 511) * 4 + (j >> 9)] = (float)acc;
}

// four 512x2048 weight permutes in one launch (z selects)
struct Perm4 { const float *i0,*i1,*i2,*i3; float *o0,*o1,*o2,*o3; int r0,r1,r2,r3; };
__global__ void permW4(Perm4 p)
{
    int j = blockIdx.x * 256 + threadIdx.x;   // 0..2047
    int k = blockIdx.y;                        // 0..511
    int z = blockIdx.z;
    const float* in = z == 0 ? p.i0 : (z == 1 ? p.i1 : (z == 2 ? p.i2 : p.i3));
    float*      out = z == 0 ? p.o0 : (z == 1 ? p.o1 : (z == 2 ? p.o2 : p.o3));
    int      rowoff = z == 0 ? p.r0 : (z == 1 ? p.r1 : (z == 2 ? p.r2 : p.r3));
    out[(size_t)k * G4 + (j & 511) * 4 + (j >> 9)] = in[(size_t)(k + rowoff) * G4 + j];
}

__global__ void init_kv(const float* __restrict__ bkvo, __hip_bfloat16* __restrict__ Kb,
                        float* __restrict__ Vb)
{
    for (ll i = (ll)blockIdx.x * 256 + threadIdx.x; i < (ll)NB * TS * D; i += (ll)gridDim.x * 256) {
        int d = (int)(i & (D - 1));
        Kb[i] = __float2bfloat16(bkvo[d]);
        Vb[i] = bkvo[D + d];
    }
}

// ---------------- gates GEMM (MFMA f64) + LSTM cell body — 64x32 tile, register prefetch ----------------
// Per-output K-order identical to r19 (sequential chunks, same 4-k MFMA slabs) + single
// f64 tab-add-then-round. Prefetch only moves WHEN loads are issued, not any arithmetic.
template<int USE2>
__device__ __forceinline__ void gates_body(
    double* smem, const float* a0, const float* a1,
    const float* B0, const float* B1,
    const float* tab, const int* idx, int idxStride,
    float* cb, float* hb, int bx, int by, int K, int useC, int dl, int tid)
{
    float* As = (float*)smem;                   // [64 m][34 k]
    float* Bs = As + 64 * 34;                   // [32 j][35 kr]
    const int row0 = by * 64, col0 = bx * 32;
    const int wave = tid >> 6, lane = tid & 63;
    const int wr = wave >> 1, wc = wave & 1;
    const int l15 = lane & 15, l4 = lane >> 4;

    f64x4 acc[2];
    acc[0] = (f64x4){0.0, 0.0, 0.0, 0.0};
    acc[1] = (f64x4){0.0, 0.0, 0.0, 0.0};

    float ra[8], rb[4];
    if (K > 0) {
#pragma unroll
        for (int l = 0; l < 8; ++l) {
            int t = tid + l * 256; int k = t & 31, m = t >> 5;
            if (USE2 && k >= D) ra[l] = a1[(size_t)(row0 + m) * D + (k - D)];
            else                ra[l] = a0[(size_t)(row0 + m) * D + k];
        }
#pragma unroll
        for (int l = 0; l < 4; ++l) {
            int t = tid + l * 256; int j = t & 31, kr = t >> 5;
            if (USE2 && kr >= D) rb[l] = B1[(size_t)(kr - D) * G4 + col0 + j];
            else                 rb[l] = B0[(size_t)kr * G4 + col0 + j];
        }
    }

    for (int k0 = 0; k0 < K; k0 += 32) {
#pragma unroll
        for (int l = 0; l < 8; ++l) {
            int t = tid + l * 256;
            As[(t >> 5) * 34 + (t & 31)] = ra[l];
        }
#pragma unroll
        for (int l = 0; l < 4; ++l) {
            int t = tid + l * 256;
            Bs[(t & 31) * 35 + (t >> 5)] = rb[l];
        }
        __syncthreads();
        if (k0 + 32 < K) {                      // prefetch next chunk while MFMA runs
            const int kn = k0 + 32;
#pragma unroll
            for (int l = 0; l < 8; ++l) {
                int t = tid + l * 256; int k = kn + (t & 31), m = t >> 5;
                if (USE2 && k >= D) ra[l] = a1[(size_t)(row0 + m) * D + (k - D)];
                else                ra[l] = a0[(size_t)(row0 + m) * D + k];
            }
#pragma unroll
            for (int l = 0; l < 4; ++l) {
                int t = tid + l * 256; int j = t & 31, kr = kn + (t >> 5);
                if (USE2 && kr >= D) rb[l] = B1[(size_t)(kr - D) * G4 + col0 + j];
                else                 rb[l] = B0[(size_t)kr * G4 + col0 + j];
            }
        }
#pragma unroll
        for (int kk4 = 0; kk4 < 8; ++kk4) {
            const int kr = kk4 * 4 + l4;
            double a0f = (double)As[(wr * 32 + l15) * 34 + kr];
            double a1f = (double)As[(wr * 32 + 16 + l15) * 34 + kr];
            double b0f = (double)Bs[(wc * 16 + l15) * 35 + kr];
            acc[0] = __builtin_amdgcn_mfma_f64_16x16x4f64(a0f, b0f, acc[0], 0, 0, 0);
            acc[1] = __builtin_amdgcn_mfma_f64_16x16x4f64(a1f, b0f, acc[1], 0, 0, 0);
        }
        __syncthreads();
    }

    // bounce acc -> f32 gates (tab added in f64, rounded once — r19-identical values)
    float* G = (float*)smem;                    // [64][33]
#pragma unroll
    for (int tr = 0; tr < 2; ++tr)
#pragma unroll
        for (int n = 0; n < 4; ++n) {
            int r, c;
            dmap(dl, l15, l4, n, r, c);
            int lr = wr * 32 + tr * 16 + r;
            int lc = wc * 16 + c;
            const float* trw = tab + (size_t)idx[(size_t)(row0 + lr) * idxStride] * G4;
            G[lr * 33 + lc] = (float)(acc[tr][n] + (double)trw[col0 + lc]);
        }
    __syncthreads();

    const int ty = tid >> 3, tx = tid & 7;
    const int d  = (col0 + tx * 4) >> 2;
#pragma unroll
    for (int i = 0; i < 2; ++i) {
        int rl  = ty * 2 + i;
        int row = row0 + rl;
        float gi = G[rl * 33 + tx * 4 + 0];
        float gf = G[rl * 33 + tx * 4 + 1];
        float gg = G[rl * 33 + tx * 4 + 2];
        float go = G[rl * 33 + tx * 4 + 3];
        float c  = useC ? cb[(size_t)row * D + d] : 0.f;
        float si = 1.f / (1.f + expf(-gi));
        float sf = 1.f / (1.f + expf(-gf));
        float so = 1.f / (1.f + expf(-go));
        c = sf * c + si * tanhf(gg);
        cb[(size_t)row * D + d] = c;
        hb[(size_t)row * D + d] = so * tanhf(c);
    }
}

// ---------------- K/V' fold body (64x64, transposed staging, register prefetch) ----------------
__device__ __forceinline__ void fold_body(
    double* smem, const float* h, const float* W, int rowoff,
    __hip_bfloat16* Kb, float* Vb, int trow, int bx, int by, int dl, int tid)
{
    float* As = (float*)smem;                   // [64 m][34 k]
    float* Bs = As + 64 * 34;                   // [64 j][35 kr]
    const int row0 = by * 64, col0 = bx * 64;
    const int wave = tid >> 6, lane = tid & 63;
    const int wr = wave >> 1, wc = wave & 1;
    const int l15 = lane & 15, l4 = lane >> 4;

    f64x4 acc[2][2];
#pragma unroll
    for (int i = 0; i < 2; ++i)
#pragma unroll
        for (int j = 0; j < 2; ++j) acc[i][j] = (f64x4){0.0, 0.0, 0.0, 0.0};

    float ra[8], rb[8];
#pragma unroll
    for (int l = 0; l < 8; ++l) {
        int t = tid + l * 256;
        { int k = t & 31, m = t >> 5; ra[l] = h[(size_t)(row0 + m) * D + k]; }
        { int j = t & 63, kr = t >> 6; rb[l] = W[(size_t)(rowoff + kr) * 1024 + col0 + j]; }
    }

    for (int k0 = 0; k0 < D; k0 += 32) {
#pragma unroll
        for (int l = 0; l < 8; ++l) {
            int t = tid + l * 256;
            As[(t >> 5) * 34 + (t & 31)] = ra[l];
            Bs[(t & 63) * 35 + (t >> 6)] = rb[l];
        }
        __syncthreads();
        if (k0 + 32 < D) {
            const int kn = k0 + 32;
#pragma unroll
            for (int l = 0; l < 8; ++l) {
                int t = tid + l * 256;
                { int k = kn + (t & 31), m = t >> 5; ra[l] = h[(size_t)(row0 + m) * D + k]; }
                { int j = t & 63, kr = kn + (t >> 6); rb[l] = W[(size_t)(rowoff + kr) * 1024 + col0 + j]; }
            }
        }
#pragma unroll
        for (int kk4 = 0; kk4 < 8; ++kk4) {
            const int kr = kk4 * 4 + l4;
            double a0f = (double)As[(wr * 32 + l15) * 34 + kr];
            double a1f = (double)As[(wr * 32 + 16 + l15) * 34 + kr];
            double b0f = (double)Bs[(wc * 32 + l15) * 35 + kr];
            double b1f = (double)Bs[(wc * 32 + 16 + l15) * 35 + kr];
            acc[0][0] = __builtin_amdgcn_mfma_f64_16x16x4f64(a0f, b0f, acc[0][0], 0, 0, 0);
            acc[0][1] = __builtin_amdgcn_mfma_f64_16x16x4f64(a0f, b1f, acc[0][1], 0, 0, 0);
            acc[1][0] = __builtin_amdgcn_mfma_f64_16x16x4f64(a1f, b0f, acc[1][0], 0, 0, 0);
            acc[1][1] = __builtin_amdgcn_mfma_f64_16x16x4f64(a1f, b1f, acc[1][1], 0, 0, 0);
        }
        __syncthreads();
    }

#pragma unroll
    for (int tr = 0; tr < 2; ++tr)
#pragma unroll
        for (int tc = 0; tc < 2; ++tc)
#pragma unroll
            for (int n = 0; n < 4; ++n) {
                int r, c;
                dmap(dl, l15, l4, n, r, c);
                int row = row0 + wr * 32 + tr * 16 + r;
                int col = col0 + wc * 32 + tc * 16 + c;
                double v = acc[tr][tc][n];
                ll ix = ((ll)row * TS + trow) * D + (col & (D - 1));
                if (col < D) {
                    double v2 = v + (double)__bfloat162float(Kb[ix]);
                    Kb[ix] = __float2bfloat16((float)v2);
                } else {
                    Vb[ix] = (float)((double)Vb[ix] + v);
                }
            }
}

// ---------------- fused ENCODER step: gates(t) 2048 tiles + fold(t-1) 512 tiles ----------------
struct EncArgs {
    const float *hFr, *hBr;
    float *hFw, *hBw, *cF, *cB;
    const float *WhPf, *WhPb, *tabPf, *tabPb;
    const int *srcF, *srcB;
    const float *WKVo;
    __hip_bfloat16 *Kb; float *Vb;
    int foldF, foldB;
    int K, useC, nG;
    const int *dlayp;
};

__global__ __launch_bounds__(256)
void enc_mega(EncArgs a)
{
    __shared__ double smem[2208];   // fold staging 17664 B is the max
    const int bid = blockIdx.x;
    const int tid = threadIdx.x;
    const int dl  = a.dlayp[0];
    if (bid < a.nG) {
        const int dir = bid >> 10;            // 0 = F, 1 = B (1024 tiles each)
        const int tt  = bid & 1023;
        gates_body<0>(smem,
                      dir ? a.hBr : a.hFr, nullptr,
                      dir ? a.WhPb : a.WhPf, nullptr,
                      dir ? a.tabPb : a.tabPf,
                      dir ? a.srcB : a.srcF, TS,
                      dir ? a.cB : a.cF,
                      dir ? a.hBw : a.hFw,
                      tt & 63, tt >> 6, a.K, a.useC, dl, tid);
    } else {
        const int ff = bid - a.nG;            // 0..511
        const int fz = ff >> 8;
        fold_body(smem, fz ? a.hBr : a.hFr, a.WKVo, fz ? D : 0,
                  a.Kb, a.Vb, fz ? a.foldB : a.foldF,
                  ff & 15, (ff >> 4) & 15, dl, tid);
    }
}

// ---------------- decoder gates launch (1024 tiles of 64x32) ----------------
struct DGArgs {
    const float *ctx, *h;
    const float *wiP, *whP, *tabP;
    const int *amax;
    float *cdec, *hw;
    const int *dlayp;
};

__global__ __launch_bounds__(256)
void dec_gates(DGArgs a)
{
    __shared__ double smem[1648];
    const int bid = blockIdx.x;     // 0..1023
    gates_body<1>(smem, a.ctx, a.h, a.wiP, a.whP, a.tabP,
                  a.amax, 1, a.cdec, a.hw, bid & 63, bid >> 6, 2 * D, 1,
                  a.dlayp[0], threadIdx.x);
}

// ---------------- attention for step 0 (r19-verbatim, 512 threads) ----------------
__global__ void attn_kernel(const float* __restrict__ qtab, const int* __restrict__ amax,
                            const __hip_bfloat16* __restrict__ Kb, const float* __restrict__ Vb,
                            float* __restrict__ aout, int step, float* __restrict__ ctx)
{
    const int b = blockIdx.x, tid = threadIdx.x;
    __shared__ float qs[D];
    __shared__ float ss[TS];
    qs[tid] = qtab[(size_t)amax[b] * D + tid];
    __syncthreads();
    const int t = tid >> 3, l8 = tid & 7;
    const __hip_bfloat16* krow = Kb + ((size_t)b * TS + t) * D;
    double acc = 0.0;
    for (int d = l8; d < D; d += 8) acc += (double)qs[d] * (double)__bfloat162float(krow[d]);
    acc += __shfl_xor(acc, 4);
    acc += __shfl_xor(acc, 2);
    acc += __shfl_xor(acc, 1);
    if (l8 == 0) ss[t] = (float)acc;
    __syncthreads();
    if (tid < TS) {
        float v = ss[tid], mx = v;
#pragma unroll
        for (int o = 32; o; o >>= 1) mx = fmaxf(mx, __shfl_xor(mx, o));
        float e = expf(v - mx), sm = e;
#pragma unroll
        for (int o = 32; o; o >>= 1) sm += __shfl_xor(sm, o);
        float sc = e / sm;
        ss[tid] = sc;
        aout[((size_t)b * TT + step) * TS + tid] = sc;
    }
    __syncthreads();
    double a = 0.0;
    const float* vcol = Vb + (size_t)b * TS * D + tid;
    for (int t2 = 0; t2 < TS; ++t2) a += (double)ss[t2] * (double)vcol[(size_t)t2 * D];
    ctx[(size_t)b * D + tid] = (float)a;
}

// ---------------- fused out_argmax(st) + attn(st+1), 512 threads, 4-wide out-proj ----------------
__global__ __launch_bounds__(512)
void out_attn(const float* __restrict__ h, const float* __restrict__ W,
              const float* __restrict__ bias, float* __restrict__ res,
              int step, int* __restrict__ amax,
              const float* __restrict__ qtab, const __hip_bfloat16* __restrict__ Kb,
              const float* __restrict__ Vb, float* __restrict__ aout,
              float* __restrict__ ctx, int doAttn)
{
    const int b = blockIdx.x, tid = threadIdx.x;
    __shared__ float hs[D];
    __shared__ double part[4][DTGT];
    __shared__ int tok;
    __shared__ float qs[D];
    __shared__ float ss[TS];

    // phase 1: out projection (4 K-partials, fixed reduce order — f64-class safe) + argmax
    hs[tid] = h[(size_t)b * D + tid];
    __syncthreads();
    {
        const int col = tid & 127, pp = tid >> 7;   // pp 0..3
        double acc = 0.0;
        const int kb = pp * 128;
        for (int k = kb; k < kb + 128; ++k)
            acc += (double)hs[k] * (double)W[(size_t)k * DTGT + col];
        part[pp][col] = acc;
    }
    __syncthreads();
    if (tid < DTGT) {
        double acc = (double)bias[tid] + part[0][tid] + part[1][tid] + part[2][tid] + part[3][tid];
        part[0][tid] = acc;
        res[((size_t)b * TT + step) * DTGT + tid] = (float)acc;
    }
    __syncthreads();
    if (tid == 0) {
        double best = part[0][0]; int bi = 0;
        for (int j = 1; j < DTGT; ++j) if (part[0][j] > best) { best = part[0][j]; bi = j; }
        amax[b] = bi;
        tok = bi;
    }
    __syncthreads();

    if (!doAttn) return;

    // phase 2: attention for step+1 (r19-verbatim arithmetic)
    qs[tid] = qtab[(size_t)tok * D + tid];
    __syncthreads();
    const int t = tid >> 3, l8 = tid & 7;
    const __hip_bfloat16* krow = Kb + ((size_t)b * TS + t) * D;
    double acc = 0.0;
    for (int d = l8; d < D; d += 8) acc += (double)qs[d] * (double)__bfloat162float(krow[d]);
    acc += __shfl_xor(acc, 4);
    acc += __shfl_xor(acc, 2);
    acc += __shfl_xor(acc, 1);
    if (l8 == 0) ss[t] = (float)acc;
    __syncthreads();
    if (tid < TS) {
        float v = ss[tid], mx = v;
#pragma unroll
        for (int o = 32; o; o >>= 1) mx = fmaxf(mx, __shfl_xor(mx, o));
        float e = expf(v - mx), sm = e;
#pragma unroll
        for (int o = 32; o; o >>= 1) sm += __shfl_xor(sm, o);
        float sc = e / sm;
        ss[tid] = sc;
        aout[((size_t)b * TT + (step + 1)) * TS + tid] = sc;
    }
    __syncthreads();
    double a = 0.0;
    const float* vcol = Vb + (size_t)b * TS * D + tid;
    for (int t2 = 0; t2 < TS; ++t2) a += (double)ss[t2] * (double)vcol[(size_t)t2 * D];
    ctx[(size_t)b * D + tid] = (float)a;
}

// ---------------- decoder init: h0/c0 (r19-verbatim) ----------------
__global__ __launch_bounds__(512)
void hc_init(const float* __restrict__ hF, const float* __restrict__ hB,
             const float* __restrict__ cF, const float* __restrict__ cB,
             const float* __restrict__ hpw, const float* __restrict__ hpb,
             const float* __restrict__ cpw, const float* __restrict__ cpb,
             float* __restrict__ h0, float* __restrict__ c0)
{
    __shared__ float s0[D], s1[D], s2[D], s3[D];
    const int b = blockIdx.x, j = threadIdx.x;
    s0[j] = hF[(size_t)b * D + j]; s1[j] = hB[(size_t)b * D + j];
    s2[j] = cF[(size_t)b * D + j]; s3[j] = cB[(size_t)b * D + j];
    __syncthreads();
    double a = (double)hpb[j];
    for (int k = 0; k < D; ++k) a += (double)s0[k] * (double)hpw[(size_t)k * D + j];
    for (int k = 0; k < D; ++k) a += (double)s1[k] * (double)hpw[(size_t)(k + D) * D + j];
    h0[(size_t)b * D + j] = (float)tanh(a);
    a = (double)cpb[j];
    for (int k = 0; k < D; ++k) a += (double)s2[k] * (double)cpw[(size_t)k * D + j];
    for (int k = 0; k < D; ++k) a += (double)s3[k] * (double)cpw[(size_t)(k + D) * D + j];
    c0[(size_t)b * D + j] = (float)tanh(a);
}

__global__ void init_amax(const int* __restrict__ tgt, int* __restrict__ amax)
{
    int b = blockIdx.x * 256 + threadIdx.x;
    if (b < NB) amax[b] = tgt[(size_t)b * TT];
}

} // namespace k77

extern "C" void kernel_launch(void* const* d_in, const int* in_sizes, int n_in,
                              void* d_out, int out_size, void* d_ws, size_t ws_size,
                              hipStream_t stream)
{
    using namespace k77;
    (void)in_sizes; (void)n_in; (void)out_size;

    const int*   src        = (const int*)  d_in[0];
    const int*   tgt        = (const int*)  d_in[1];
    const float* enc_emb_w  = (const float*)d_in[2];
    const float* enc_wi_f   = (const float*)d_in[3];
    const float* enc_wh_f   = (const float*)d_in[4];
    const float* enc_bi_f   = (const float*)d_in[5];
    const float* enc_bh_f   = (const float*)d_in[6];
    const float* enc_wi_b   = (const float*)d_in[7];
    const float* enc_wh_b   = (const float*)d_in[8];
    const float* enc_bi_b   = (const float*)d_in[9];
    const float* enc_bh_b   = (const float*)d_in[10];
    const float* enc_post_w = (const float*)d_in[11];
    const float* enc_post_b = (const float*)d_in[12];
    const float* h_post_w   = (const float*)d_in[13];
    const float* h_post_b   = (const float*)d_in[14];
    const float* c_post_w   = (const float*)d_in[15];
    const float* c_post_b   = (const float*)d_in[16];
    const float* wq_w       = (const float*)d_in[17];
    const float* wq_b       = (const float*)d_in[18];
    const float* wk_w       = (const float*)d_in[19];
    const float* wk_b       = (const float*)d_in[20];
    const float* wv_w       = (const float*)d_in[21];
    const float* wv_b       = (const float*)d_in[22];
    const float* wo_w       = (const float*)d_in[23];
    const float* wo_b       = (const float*)d_in[24];
    const float* dec_emb_w  = (const float*)d_in[25];
    const float* dec_wi     = (const float*)d_in[26];
    const float* dec_wh     = (const float*)d_in[27];
    const float* dec_bi     = (const float*)d_in[28];
    const float* dec_bh     = (const float*)d_in[29];
    const float* dec_post_w = (const float*)d_in[30];
    const float* dec_post_b = (const float*)d_in[31];

    float* ws = (float*)d_ws;
    size_t off = 0;
    auto alloc = [&](size_t n) { float* p = ws + off; off += n; return p; };
    float* hF0     = alloc((size_t)NB * D);
    float* hF1     = alloc((size_t)NB * D);
    float* hB0     = alloc((size_t)NB * D);
    float* hB1     = alloc((size_t)NB * D);
    float* cF      = alloc((size_t)NB * D);
    float* cB      = alloc((size_t)NB * D);
    float* hd0     = alloc((size_t)NB * D);
    float* hd1     = alloc((size_t)NB * D);
    float* cdec    = alloc((size_t)NB * D);
    float* ctxb    = alloc((size_t)NB * D);
    float* tabPf   = alloc((size_t)128 * G4);
    float* tabPb   = alloc((size_t)128 * G4);
    float* dec_tabP= alloc((size_t)128 * G4);
    float* q_tab   = alloc((size_t)128 * D);
    float* WKVo    = alloc((size_t)1024 * 1024);
    float* bkvo    = alloc(1024);
    float* WhPf    = alloc((size_t)D * G4);
    float* WhPb    = alloc((size_t)D * G4);
    float* dec_wiP = alloc((size_t)D * G4);
    float* dec_whP = alloc((size_t)D * G4);
    float* Wv_tmp  = alloc((size_t)1024 * D);
    float* bv_tmp  = alloc(D);
    int*   amax    = (int*)alloc(1024);
    int*   dlayD   = (int*)alloc(64);

    const size_t commonF = off;
    const size_t kvCnt   = (size_t)NB * TS * D;
    const size_t need    = commonF * 4 + kvCnt * 2 + kvCnt * 4;   // ~249 MB

    if (ws_size < need) {
        hipMemsetAsync(d_out, 0x7F, 1024, stream);   // sentinel: ws too small
        return;
    }
    __hip_bfloat16* Kh = (__hip_bfloat16*)(ws + commonF);
    float*          Vf = (float*)((char*)Kh + kvCnt * 2);

    float* attn_out = (float*)d_out;
    float* res_out  = attn_out + (size_t)NB * TT * TS;

    const float scale = 0.044194173824159216f;   // 512^-0.5

    float* hFbuf[2] = {hF0, hF1};
    float* hBbuf[2] = {hB0, hB1};
    float* hd[2]    = {hd0, hd1};

    // ---------- MFMA layout probe ----------
    probe_mfma<<<1, 64, 0, stream>>>(dlayD);
    dlay_check<<<1, 64, 0, stream>>>(dlayD, attn_out);

    // ---------- precompute ----------
    Tab3 t3;
    t3.A0 = enc_emb_w; t3.A1 = enc_emb_w; t3.A2 = dec_emb_w;
    t3.B0 = enc_wi_f;  t3.B1 = enc_wi_b;  t3.B2 = dec_wi;
    t3.p0 = enc_bi_f;  t3.p1 = enc_bi_b;  t3.p2 = dec_bi;
    t3.q0 = enc_bh_f;  t3.q1 = enc_bh_b;  t3.q2 = dec_bh;
    t3.C0 = tabPf;     t3.C1 = tabPb;     t3.C2 = dec_tabP;
    tab3_gemm64<<<dim3(8, 128, 3), 256, 0, stream>>>(t3);
    tab_gemm64<<<dim3(2, 128), 256, 0, stream>>>(dec_emb_w, wq_w, wq_b, nullptr, q_tab, 128, D, D, D, scale, 0);
    tab_gemm64<<<dim3(2, 1024), 256, 0, stream>>>(enc_post_w, wk_w, nullptr, nullptr, WKVo, 1024, D, D, 1024, 1.f, 0);
    tab_gemm64<<<dim3(2, 1024), 256, 0, stream>>>(enc_post_w, wv_w, nullptr, nullptr, Wv_tmp, 1024, D, D, D, 1.f, 0);
    tab_gemm64<<<dim3(2, 1024), 256, 0, stream>>>(Wv_tmp, wo_w, nullptr, nullptr, WKVo + D, 1024, D, D, 1024, 1.f, 0);
    tab_gemm64<<<dim3(2, 1), 256, 0, stream>>>(enc_post_b, wk_w, wk_b, nullptr, bkvo, 1, D, D, D, 1.f, 0);
    tab_gemm64<<<dim3(2, 1), 256, 0, stream>>>(enc_post_b, wv_w, wv_b, nullptr, bv_tmp, 1, D, D, D, 1.f, 0);
    tab_gemm64<<<dim3(2, 1), 256, 0, stream>>>(bv_tmp, wo_w, wo_b, nullptr, bkvo + D, 1, D, D, D, 1.f, 0);
    Perm4 p4;
    p4.i0 = enc_wh_f; p4.o0 = WhPf;    p4.r0 = 0;
    p4.i1 = enc_wh_b; p4.o1 = WhPb;    p4.r1 = 0;
    p4.i2 = dec_wi;   p4.o2 = dec_wiP; p4.r2 = 512;
    p4.i3 = dec_wh;   p4.o3 = dec_whP; p4.r3 = 0;
    permW4<<<dim3(8, 512, 4), 256, 0, stream>>>(p4);
    init_kv<<<2048, 256, 0, stream>>>(bkvo, Kh, Vf);

    // ---------- encoder: 65 fused launches (gates(t) + fold(t-1)) ----------
    for (int t = 0; t < TS; ++t) {
        EncArgs ea;
        ea.hFr = hFbuf[t & 1]; ea.hBr = hBbuf[t & 1];
        ea.hFw = hFbuf[(t + 1) & 1]; ea.hBw = hBbuf[(t + 1) & 1];
        ea.cF = cF; ea.cB = cB;
        ea.WhPf = WhPf; ea.WhPb = WhPb; ea.tabPf = tabPf; ea.tabPb = tabPb;
        ea.srcF = src + t; ea.srcB = src + (TS - 1 - t);
        ea.WKVo = WKVo; ea.Kb = Kh; ea.Vb = Vf;
        ea.foldF = t - 1; ea.foldB = TS - t;
        ea.K = t ? D : 0; ea.useC = t ? 1 : 0; ea.nG = 2048;
        ea.dlayp = dlayD;
        const int grid = 2048 + (t ? 512 : 0);
        enc_mega<<<grid, 256, 0, stream>>>(ea);
    }
    {   // final fold for step 63
        EncArgs ea;
        ea.hFr = hFbuf[0]; ea.hBr = hBbuf[0];
        ea.hFw = nullptr; ea.hBw = nullptr; ea.cF = cF; ea.cB = cB;
        ea.WhPf = WhPf; ea.WhPb = WhPb; ea.tabPf = tabPf; ea.tabPb = tabPb;
        ea.srcF = src; ea.srcB = src;
        ea.WKVo = WKVo; ea.Kb = Kh; ea.Vb = Vf;
        ea.foldF = 63; ea.foldB = 0;
        ea.K = 0; ea.useC = 0; ea.nG = 0;
        ea.dlayp = dlayD;
        enc_mega<<<512, 256, 0, stream>>>(ea);
    }

    // ---------- decoder initial h, c ----------
    hc_init<<<NB, 512, 0, stream>>>(hFbuf[0], hBbuf[0], cF, cB,
                                    h_post_w, h_post_b, c_post_w, c_post_b, hd0, cdec);
    init_amax<<<4, 256, 0, stream>>>(tgt, amax);

    // ---------- decoder: attn(0) + 64x(gates; out+attn) ----------
    attn_kernel<<<NB, 512, 0, stream>>>(q_tab, amax, Kh, Vf, attn_out, 0, ctxb);
    for (int st = 0; st < TT; ++st) {
        DGArgs da;
        da.ctx = ctxb; da.h = hd[st & 1];
        da.wiP = dec_wiP; da.whP = dec_whP; da.tabP = dec_tabP;
        da.amax = amax; da.cdec = cdec; da.hw = hd[(st + 1) & 1];
        da.dlayp = dlayD;
        dec_gates<<<1024, 256, 0, stream>>>(da);
        out_attn<<<NB, 512, 0, stream>>>(hd[(st + 1) & 1], dec_post_w, dec_post_b, res_out,
                                         st, amax, q_tab, Kh, Vf, attn_out, ctxb,
                                         st < TT - 1 ? 1 : 0);
    }
}